// Round 6
// baseline (218.875 us; speedup 1.0000x reference)
//
#include <hip/hip_runtime.h>

typedef unsigned short ushort_t;
typedef __attribute__((ext_vector_type(8))) short short8;
typedef __attribute__((ext_vector_type(4))) float f32x4;
typedef __attribute__((ext_vector_type(16))) float f32x16;
typedef __attribute__((ext_vector_type(2))) unsigned uint2v;
typedef __attribute__((ext_vector_type(4))) unsigned uint4v;

#define LOG2E 1.44269504088896f

// async global->LDS, 16B per lane. LDS dest must be wave-uniform base + lane*16.
__device__ __forceinline__ void async16(const void* g, void* l) {
  __builtin_amdgcn_global_load_lds(
      (const __attribute__((address_space(1))) void*)g,
      (__attribute__((address_space(3))) void*)l, 16, 0, 0);
}

__device__ __forceinline__ ushort_t f2bf(float f) {
  union { float f; unsigned u; } x; x.f = f;
  unsigned u = x.u;
  u += 0x7fffu + ((u >> 16) & 1u);
  return (ushort_t)(u >> 16);
}

__device__ __forceinline__ float bf2f(ushort_t w) {
  union { unsigned u; float f; } x; x.u = ((unsigned)w) << 16;
  return x.f;
}

__device__ __forceinline__ short8 u4s8(uint4v u) { union { uint4v a; short8 b; } c; c.a = u; return c.b; }
__device__ __forceinline__ uint4v s8u4(short8 s) { union { short8 a; uint4v b; } c; c.a = s; return c.b; }
__device__ __forceinline__ unsigned fu(float f) { union { float a; unsigned b; } c; c.a = f; return c.b; }

__device__ __forceinline__ f32x16 zero16() {
  f32x16 v;
  #pragma unroll
  for (int i = 0; i < 16; i++) v[i] = 0.f;
  return v;
}

// ------------- merged ingest: weight transpose+split AND activation split ----
__global__ __launch_bounds__(256) void prep_all(const float* __restrict__ cur,
                                                const float* __restrict__ hid,
                                                const float* __restrict__ Wq,
                                                const float* __restrict__ Wkv,
                                                const float* __restrict__ Wo,
                                                ushort_t* __restrict__ ch, ushort_t* __restrict__ cl,
                                                ushort_t* __restrict__ hh, ushort_t* __restrict__ hl,
                                                ushort_t* __restrict__ qh, ushort_t* __restrict__ ql,
                                                ushort_t* __restrict__ kvh, ushort_t* __restrict__ kvl,
                                                ushort_t* __restrict__ oh, ushort_t* __restrict__ ol) {
  __shared__ float tile[32][33];
  int bid = blockIdx.x;
  if (bid >= 1024) {
    // ---- activation split path ----
    int i = (bid - 1024) * 256 + threadIdx.x;       // 0 .. 2*524288-1
    const float* src;
    ushort_t *hi, *lo;
    int j;
    if (i < 524288) { src = cur; hi = ch; lo = cl; j = i; }
    else            { src = hid; hi = hh; lo = hl; j = i - 524288; }
    const f32x4* s = (const f32x4*)src;
    f32x4 a = s[j * 2], b = s[j * 2 + 1];
    short8 ohh, oll;
    #pragma unroll
    for (int k = 0; k < 4; k++) {
      ushort_t h = f2bf(a[k]); ohh[k] = (short)h; oll[k] = (short)f2bf(a[k] - bf2f(h));
      h = f2bf(b[k]); ohh[k + 4] = (short)h; oll[k + 4] = (short)f2bf(b[k] - bf2f(h));
    }
    ((short8*)hi)[j] = ohh;
    ((short8*)lo)[j] = oll;
    return;
  }
  // ---- weight transpose+split path ----
  const float* src; ushort_t *dh, *dl; int Nn, bx, by;
  const int K = 512;
  if (bid < 256)      { src = Wq;  dh = qh;  dl = ql;  Nn = 512;  bx = (bid & 15) * 32; by = (bid >> 4) * 32; }
  else if (bid < 768) { int b = bid - 256; src = Wkv; dh = kvh; dl = kvl; Nn = 1024; bx = (b & 31) * 32; by = (b >> 5) * 32; }
  else                { int b = bid - 768; src = Wo;  dh = oh;  dl = ol;  Nn = 512;  bx = (b & 15) * 32; by = (b >> 4) * 32; }
  int tx = threadIdx.x & 31, ty = threadIdx.x >> 5;   // (32, 8)
  #pragma unroll
  for (int i = 0; i < 32; i += 8)
    tile[ty + i][tx] = src[(size_t)(by + ty + i) * Nn + bx + tx];
  __syncthreads();
  #pragma unroll
  for (int i = 0; i < 32; i += 8) {
    float v = tile[tx][ty + i];
    ushort_t h = f2bf(v);
    size_t idx = (size_t)(bx + ty + i) * K + by + tx;
    dh[idx] = h;
    dl[idx] = f2bf(v - bf2f(h));
  }
}

// ---- split GEMM body: C = (Ah+Al)[M][K] @ (Bh+Bl)[Nn][K]^T, 3-product ----
// BM=64, BN=128, 4 waves (2x2); wave tile 32x64. T4 counted-vmcnt pipeline.
// T2 LDS swizzle (both-sides): stage pre-swizzles the GLOBAL source column
// (kc ^= (row>>1)&3, LDS dest stays linear for global_load_lds); fragment
// reads apply the same XOR. Quarter-wave then hits 8 distinct (half,chunk)
// bank positions x 2 rows = 2-way (free) instead of 8-way.
template<int EPI>
__device__ __forceinline__ void gemm3_body(const ushort_t* __restrict__ Ah,
                                           const ushort_t* __restrict__ Al,
                                           const ushort_t* __restrict__ Bh,
                                           const ushort_t* __restrict__ Bl,
                                           ushort_t* __restrict__ o_hi,
                                           ushort_t* __restrict__ o_lo,
                                           ushort_t* __restrict__ o_vt,
                                           float* __restrict__ outf,
                                           int K, int ldo, int m0, int n0,
                                           ushort_t* lds) {
  constexpr int MT = 2, TN = 4;
  ushort_t* Ash = lds;            // [2][2048]
  ushort_t* Asl = lds + 4096;     // [2][2048]
  ushort_t* Bsh = lds + 8192;     // [2][4096]
  ushort_t* Bsl = lds + 16384;    // [2][4096]
  const int tid = threadIdx.x;
  const int wave = tid >> 6, lane = tid & 63;
  const int wm = (wave >> 1) * 32, wn = (wave & 1) * 64;
  const int lrow = lane & 15, lq = lane >> 4;

  f32x4 acc[MT][TN];
  const f32x4 z = {0.f, 0.f, 0.f, 0.f};
  #pragma unroll
  for (int i = 0; i < MT; i++)
    #pragma unroll
    for (int j = 0; j < TN; j++) acc[i][j] = z;

  auto stage = [&](int k0, int d) {
    const int aoff = d * 2048, boff = d * 4096;
    {                                     // A tile: 64 rows x 4 chunks
      int r = tid >> 2, kc = tid & 3;
      int kcs = kc ^ ((r >> 1) & 3);      // pre-swizzled source chunk
      size_t ga = (size_t)(m0 + r) * K + k0 + kcs * 8;
      async16(&Ah[ga], &Ash[aoff + tid * 8]);
      async16(&Al[ga], &Asl[aoff + tid * 8]);
    }
    #pragma unroll
    for (int i = 0; i < 2; i++) {         // B tile: 128 rows x 4 chunks
      int g = i * 256 + tid;
      int r = g >> 2, kc = g & 3;
      int kcs = kc ^ ((r >> 1) & 3);
      size_t gb = (size_t)(n0 + r) * K + k0 + kcs * 8;
      async16(&Bh[gb], &Bsh[boff + g * 8]);
      async16(&Bl[gb], &Bsl[boff + g * 8]);
    }
  };

  stage(0, 0);
  int cur = 0;
  for (int k0 = 0; k0 < K; k0 += 32) {
    if (k0 + 32 < K) {
      stage(k0 + 32, cur ^ 1);   // 6 loads/thread, stay in flight across barrier
      asm volatile("s_waitcnt vmcnt(6)" ::: "memory");   // tile k0 landed
    } else {
      asm volatile("s_waitcnt vmcnt(0)" ::: "memory");
    }
    __builtin_amdgcn_s_barrier();

    const int ab = cur * 2048, bb = cur * 4096;
    // swizzled read offsets (chunk = lq ^ ((row>>1)&3))
    int aro[MT], bro[TN];
    #pragma unroll
    for (int t = 0; t < MT; t++) {
      int row = wm + t * 16 + lrow;
      aro[t] = row * 32 + (lq ^ ((row >> 1) & 3)) * 8;
    }
    #pragma unroll
    for (int t = 0; t < TN; t++) {
      int row = wn + t * 16 + lrow;
      bro[t] = row * 32 + (lq ^ ((row >> 1) & 3)) * 8;
    }

    short8 afh[MT], bfr[TN];
    #pragma unroll
    for (int t = 0; t < MT; t++)
      afh[t] = *(const short8*)&Ash[ab + aro[t]];
    #pragma unroll
    for (int t = 0; t < TN; t++)
      bfr[t] = *(const short8*)&Bsh[bb + bro[t]];
    #pragma unroll
    for (int ti = 0; ti < MT; ti++)
      #pragma unroll
      for (int tj = 0; tj < TN; tj++)
        acc[ti][tj] = __builtin_amdgcn_mfma_f32_16x16x32_bf16(afh[ti], bfr[tj], acc[ti][tj], 0, 0, 0);

    {
      short8 afl[MT];
      #pragma unroll
      for (int t = 0; t < MT; t++)
        afl[t] = *(const short8*)&Asl[ab + aro[t]];
      #pragma unroll
      for (int ti = 0; ti < MT; ti++)
        #pragma unroll
        for (int tj = 0; tj < TN; tj++)
          acc[ti][tj] = __builtin_amdgcn_mfma_f32_16x16x32_bf16(afl[ti], bfr[tj], acc[ti][tj], 0, 0, 0);
    }
    #pragma unroll
    for (int t = 0; t < TN; t++)
      bfr[t] = *(const short8*)&Bsl[bb + bro[t]];
    #pragma unroll
    for (int ti = 0; ti < MT; ti++)
      #pragma unroll
      for (int tj = 0; tj < TN; tj++)
        acc[ti][tj] = __builtin_amdgcn_mfma_f32_16x16x32_bf16(afh[ti], bfr[tj], acc[ti][tj], 0, 0, 0);

    if (k0 + 32 < K) {   // readers done before next iter's stage overwrites buf
      asm volatile("s_waitcnt lgkmcnt(0)" ::: "memory");
      __builtin_amdgcn_s_barrier();
    }
    cur ^= 1;
  }

  // epilogue
  #pragma unroll
  for (int ti = 0; ti < MT; ti++) {
    #pragma unroll
    for (int tj = 0; tj < TN; tj++) {
      int row0 = m0 + wm + ti * 16 + lq * 4;
      int col = n0 + wn + tj * 16 + lrow;
      #pragma unroll
      for (int r = 0; r < 4; r++) {
        int m = row0 + r;
        float fv = acc[ti][tj][r];
        if (EPI == 0) {
          size_t idx = (size_t)((m >> 10) * 8 + (col >> 6)) * 65536 + (m & 1023) * 64 + (col & 63);
          ushort_t h = f2bf(fv);
          o_hi[idx] = h;
          o_lo[idx] = f2bf(fv - bf2f(h));
        } else if (EPI == 1) {
          if (col < 512) {
            size_t idx = (size_t)((m >> 10) * 8 + (col >> 6)) * 65536 + (m & 1023) * 64 + (col & 63);
            ushort_t h = f2bf(fv);
            o_hi[idx] = h;
            o_lo[idx] = f2bf(fv - bf2f(h));
          } else {
            int cc = col - 512;
            o_vt[(size_t)(((m >> 10) * 8 + (cc >> 6)) * 64 + (cc & 63)) * 1024 + (m & 1023)] = f2bf(fv);
          }
        } else {
          outf[(size_t)m * ldo + col] = fv;   // fp32 final output
        }
      }
    }
  }
}

// merged q+kv projection: 1536 blocks, XCD-bijective remap (1536 = 8*192).
__global__ __launch_bounds__(256) void gemm_qkv(const ushort_t* __restrict__ Hh,
                                                const ushort_t* __restrict__ Hl,
                                                const ushort_t* __restrict__ WkvTh,
                                                const ushort_t* __restrict__ WkvTl,
                                                ushort_t* __restrict__ kh,
                                                ushort_t* __restrict__ kl,
                                                ushort_t* __restrict__ vt,
                                                const ushort_t* __restrict__ Chp,
                                                const ushort_t* __restrict__ Clp,
                                                const ushort_t* __restrict__ WqTh,
                                                const ushort_t* __restrict__ WqTl,
                                                ushort_t* __restrict__ qhb,
                                                ushort_t* __restrict__ qlb) {
  __shared__ __align__(16) ushort_t lds[24576];
  int bid = blockIdx.x;
  int w = (bid & 7) * 192 + (bid >> 3);      // contiguous work per XCD
  if (w < 1024) {
    int n0 = (w & 7) * 128, m0 = (w >> 3) * 64;
    gemm3_body<1>(Hh, Hl, WkvTh, WkvTl, kh, kl, vt, (float*)nullptr, 512, 0, m0, n0, lds);
  } else {
    int ww = w - 1024;
    int n0 = (ww & 3) * 128, m0 = (ww >> 2) * 64;
    gemm3_body<0>(Chp, Clp, WqTh, WqTl, qhb, qlb, (ushort_t*)nullptr, (float*)nullptr, 512, 0, m0, n0, lds);
  }
}

// output projection: 512 blocks, XCD-bijective remap (512 = 8*64), fp32 out.
__global__ __launch_bounds__(256) void gemm_o(const ushort_t* __restrict__ Ah,
                                              const ushort_t* __restrict__ Al,
                                              const ushort_t* __restrict__ Bh,
                                              const ushort_t* __restrict__ Bl,
                                              float* __restrict__ outf) {
  __shared__ __align__(16) ushort_t lds[24576];
  int bid = blockIdx.x;
  int w = (bid & 7) * 64 + (bid >> 3);
  int n0 = (w & 3) * 128, m0 = (w >> 2) * 64;
  gemm3_body<2>(Ah, Al, Bh, Bl, (ushort_t*)nullptr, (ushort_t*)nullptr,
                (ushort_t*)nullptr, outf, 512, 512, m0, n0, lds);
}

// ---------------- flash attention v5 + counted-vmcnt pipeline ----------
// 512 blocks: bh = blk & 63 (all 8 q-tiles of a head share blk%8 -> one XCD).
// 4 waves x 32 q-rows. QK^T swapped (S^T via mfma32(K,Q)); in-register softmax;
// P via cvt_pk + permlane32_swap; PV swapped (O^T via mfma32(V^T,P)).
// K/V staged via global_load_lds, pre-swizzled source (chunk ^= row&7).
// T4: stage(t+1); vmcnt(6); barrier; compute(t); lgkmcnt(0); barrier.
__global__ __launch_bounds__(256, 2) void flash_attn(const ushort_t* __restrict__ qh,
                                                     const ushort_t* __restrict__ ql,
                                                     const ushort_t* __restrict__ kh,
                                                     const ushort_t* __restrict__ kl,
                                                     const ushort_t* __restrict__ vtb,
                                                     ushort_t* __restrict__ obh,
                                                     ushort_t* __restrict__ obl) {
  __shared__ __align__(16) ushort_t Ksh[2][64 * 64];
  __shared__ __align__(16) ushort_t Ksl[2][64 * 64];
  __shared__ __align__(16) ushort_t VTs[2][64 * 64];

  const int tid = threadIdx.x;
  const int wave = tid >> 6, lane = tid & 63;
  const int bh = blockIdx.x & 63, qt = blockIdx.x >> 6;
  const int l31 = lane & 31, hi = lane >> 5;

  const ushort_t* Qh = qh + (size_t)bh * 65536;
  const ushort_t* Ql = ql + (size_t)bh * 65536;
  const ushort_t* Kph = kh + (size_t)bh * 65536;
  const ushort_t* Kpl = kl + (size_t)bh * 65536;
  const ushort_t* VT = vtb + (size_t)bh * 65536;

  const int qrow0 = qt * 128 + wave * 32;

  // Q fragments (B-operand: col q = l31, contraction d = ds*16 + hi*8 + 0..7)
  short8 qfh[4], qfl[4];
  #pragma unroll
  for (int ds = 0; ds < 4; ds++) {
    size_t idx = (size_t)(qrow0 + l31) * 64 + ds * 16 + hi * 8;
    qfh[ds] = *(const short8*)&Qh[idx];
    qfl[ds] = *(const short8*)&Ql[idx];
  }

  f32x16 oacc[2];                 // O^T: [dtile]; row d, col q = l31
  oacc[0] = zero16();
  oacc[1] = zero16();
  float m_i = -1e30f, l_i = 0.f;  // per q = qrow0 + l31 (replicated over hi)

  // swizzled-read offsets: phys chunk = (2*i + hi) ^ (l31 & 7); i = ds or ks
  const int r7 = l31 & 7;
  int pc[4];
  #pragma unroll
  for (int i = 0; i < 4; i++) pc[i] = (((2 * i + hi) ^ r7) << 3);
  const int ro0 = l31 * 64, ro1 = ro0 + 2048;   // rows l31 and 32+l31

  // stage kt-tile into buffer d: linear LDS dest, inverse-swizzled global src
  auto stage = [&](int kt, int d) {
    #pragma unroll
    for (int i = 0; i < 2; i++) {
      int g = i * 256 + tid, rw = g >> 3, ch = g & 7;
      int co = ((ch ^ (rw & 7)) << 3);           // swizzled source column
      int lofs = rw * 64 + (ch << 3);            // linear LDS offset
      size_t kidx = (size_t)(kt * 64 + rw) * 64 + co;
      async16(&Kph[kidx], &Ksh[d][lofs]);
      async16(&Kpl[kidx], &Ksl[d][lofs]);
      async16(&VT[(size_t)rw * 1024 + kt * 64 + co], &VTs[d][lofs]);
    }
  };

  stage(0, 0);

  for (int kt = 0; kt < 16; kt++) {
    const int cur = kt & 1;
    if (kt < 15) {
      stage(kt + 1, cur ^ 1);     // 6 loads/thread, in flight across barrier
      asm volatile("s_waitcnt vmcnt(6)" ::: "memory");   // tile kt landed
    } else {
      asm volatile("s_waitcnt vmcnt(0)" ::: "memory");
    }
    __builtin_amdgcn_s_barrier();

    // ---- QK^T: sacc[T] = S^T tile (rows k=32T.., cols q) , 3 rails ----
    f32x16 sacc0 = zero16(), sacc1 = zero16();
    __builtin_amdgcn_s_setprio(1);
    #pragma unroll
    for (int ds = 0; ds < 4; ds++) {
      short8 kh0 = *(const short8*)&Ksh[cur][ro0 + pc[ds]];
      short8 kh1 = *(const short8*)&Ksh[cur][ro1 + pc[ds]];
      sacc0 = __builtin_amdgcn_mfma_f32_32x32x16_bf16(kh0, qfh[ds], sacc0, 0, 0, 0);
      sacc1 = __builtin_amdgcn_mfma_f32_32x32x16_bf16(kh1, qfh[ds], sacc1, 0, 0, 0);
      sacc0 = __builtin_amdgcn_mfma_f32_32x32x16_bf16(kh0, qfl[ds], sacc0, 0, 0, 0);
      sacc1 = __builtin_amdgcn_mfma_f32_32x32x16_bf16(kh1, qfl[ds], sacc1, 0, 0, 0);
      short8 kl0 = *(const short8*)&Ksl[cur][ro0 + pc[ds]];
      short8 kl1 = *(const short8*)&Ksl[cur][ro1 + pc[ds]];
      sacc0 = __builtin_amdgcn_mfma_f32_32x32x16_bf16(kl0, qfh[ds], sacc0, 0, 0, 0);
      sacc1 = __builtin_amdgcn_mfma_f32_32x32x16_bf16(kl1, qfh[ds], sacc1, 0, 0, 0);
    }
    __builtin_amdgcn_s_setprio(0);

    // ---- in-register online softmax (q = l31; reduce across hi-halves) ----
    float mx = -1e30f;
    #pragma unroll
    for (int r = 0; r < 16; r++) {
      mx = fmaxf(mx, sacc0[r]);
      mx = fmaxf(mx, sacc1[r]);
    }
    mx = fmaxf(mx, __shfl_xor(mx, 32));
    float mnew = fmaxf(m_i, mx);
    float mL = mnew * LOG2E;
    float alpha = exp2f(fmaf(m_i, LOG2E, -mL));
    float sum = 0.f;
    unsigned pw[16];
    #pragma unroll
    for (int j = 0; j < 8; j++) {
      float p0 = exp2f(fmaf(sacc0[2 * j], LOG2E, -mL));
      float p1 = exp2f(fmaf(sacc0[2 * j + 1], LOG2E, -mL));
      sum += p0 + p1;
      asm("v_cvt_pk_bf16_f32 %0, %1, %2" : "=v"(pw[j]) : "v"(p0), "v"(p1));
    }
    #pragma unroll
    for (int j = 0; j < 8; j++) {
      float p0 = exp2f(fmaf(sacc1[2 * j], LOG2E, -mL));
      float p1 = exp2f(fmaf(sacc1[2 * j + 1], LOG2E, -mL));
      sum += p0 + p1;
      asm("v_cvt_pk_bf16_f32 %0, %1, %2" : "=v"(pw[8 + j]) : "v"(p0), "v"(p1));
    }
    sum += __shfl_xor(sum, 32);
    l_i = fmaf(l_i, alpha, sum);
    m_i = mnew;
    #pragma unroll
    for (int r = 0; r < 16; r++) {
      oacc[0][r] *= alpha;
      oacc[1][r] *= alpha;
    }

    // ---- PV: oacc[dt] += mfma32(V^T-frag, P-frag) ----
    __builtin_amdgcn_s_setprio(1);
    #pragma unroll
    for (int ks = 0; ks < 4; ks++) {
      const int base = (ks >> 1) * 8 + (ks & 1) * 4;
      uint2v s0 = __builtin_amdgcn_permlane32_swap(pw[base + 0], pw[base + 2], false, false);
      uint2v s1 = __builtin_amdgcn_permlane32_swap(pw[base + 1], pw[base + 3], false, false);
      short8 pfrag = u4s8((uint4v){s0.x, s1.x, s0.y, s1.y});
      short8 vf0 = *(const short8*)&VTs[cur][ro0 + pc[ks]];
      short8 vf1 = *(const short8*)&VTs[cur][ro1 + pc[ks]];
      oacc[0] = __builtin_amdgcn_mfma_f32_32x32x16_bf16(vf0, pfrag, oacc[0], 0, 0, 0);
      oacc[1] = __builtin_amdgcn_mfma_f32_32x32x16_bf16(vf1, pfrag, oacc[1], 0, 0, 0);
    }
    __builtin_amdgcn_s_setprio(0);

    if (kt < 15) {   // readers done before next iter's stage overwrites buf
      asm volatile("s_waitcnt lgkmcnt(0)" ::: "memory");
      __builtin_amdgcn_s_barrier();
    }
  }

  // ---- epilogue: lane-local 1/l, uint2 stores ----
  const int b = bh >> 3, h = bh & 7;
  const int n = qrow0 + l31;
  float rinv = 1.f / l_i;
  #pragma unroll
  for (int dt = 0; dt < 2; dt++) {
    #pragma unroll
    for (int t = 0; t < 4; t++) {
      ushort_t hv[4], lv[4];
      #pragma unroll
      for (int e = 0; e < 4; e++) {
        float x = oacc[dt][4 * t + e] * rinv;
        hv[e] = f2bf(x);
        lv[e] = f2bf(x - bf2f(hv[e]));
      }
      size_t idx = (size_t)(b * 1024 + n) * 512 + h * 64 + dt * 32 + t * 8 + hi * 4;
      *(uint2v*)&obh[idx] = (uint2v){(unsigned)hv[0] | ((unsigned)hv[1] << 16),
                                     (unsigned)hv[2] | ((unsigned)hv[3] << 16)};
      *(uint2v*)&obl[idx] = (uint2v){(unsigned)lv[0] | ((unsigned)lv[1] << 16),
                                     (unsigned)lv[2] | ((unsigned)lv[3] << 16)};
    }
  }
}

// ---------------- launcher ----------------
extern "C" void kernel_launch(void* const* d_in, const int* in_sizes, int n_in,
                              void* d_out, int out_size, void* d_ws, size_t ws_size,
                              hipStream_t stream) {
  const float* cur = (const float*)d_in[0];   // [8,1024,512] fp32
  const float* hid = (const float*)d_in[1];   // [8,1024,512] fp32
  const float* Wq  = (const float*)d_in[2];   // [512,512]
  const float* Wkv = (const float*)d_in[3];   // [512,1024]
  const float* Wo  = (const float*)d_in[4];   // [512,512]

  ushort_t* ws = (ushort_t*)d_ws;
  ushort_t* Ch = ws;                    // 4,194,304  (cur split; reused: aout hi)
  ushort_t* Cl = Ch + 4194304;          // 4,194,304  (cur split; reused: aout lo)
  ushort_t* Hh = Cl + 4194304;          // 4,194,304  (hid split)
  ushort_t* Hl = Hh + 4194304;          // 4,194,304
  ushort_t* kh = Hl + 4194304;          // 4,194,304
  ushort_t* kl = kh + 4194304;          // 4,194,304
  ushort_t* vt = kl + 4194304;          // 4,194,304
  ushort_t* qhb = vt + 4194304;         // 4,194,304
  ushort_t* qlb = qhb + 4194304;        // 4,194,304
  ushort_t* WqTh = qlb + 4194304;       // 262,144
  ushort_t* WqTl = WqTh + 262144;       // 262,144
  ushort_t* WkvTh = WqTl + 262144;      // 524,288
  ushort_t* WkvTl = WkvTh + 524288;     // 524,288
  ushort_t* WoTh = WkvTl + 524288;      // 262,144
  ushort_t* WoTl = WoTh + 262144;       // 262,144

  // merged ingest: weight transpose (blocks 0..1023) + activation split (1024..5119)
  prep_all<<<5120, 256, 0, stream>>>(cur, hid, Wq, Wkv, Wo,
                                     Ch, Cl, Hh, Hl,
                                     WqTh, WqTl, WkvTh, WkvTl, WoTh, WoTl);

  // merged kv + q projections: 1536 blocks, XCD-contiguous work
  gemm_qkv<<<1536, 256, 0, stream>>>(Hh, Hl, WkvTh, WkvTl, kh, kl, vt,
                                     Ch, Cl, WqTh, WqTl, qhb, qlb);

  // attention: 512 blocks (head-major XCD grouping), 128 q-rows/block
  flash_attn<<<512, 256, 0, stream>>>(qhb, qlb, kh, kl, vt, Ch, Cl);

  // output projection: 512 blocks -> fp32 d_out
  gemm_o<<<512, 256, 0, stream>>>(Ch, Cl, WoTh, WoTl, (float*)d_out);
}

// Round 7
// 170.010 us; speedup vs baseline: 1.2874x; 1.2874x over previous
//
#include <hip/hip_runtime.h>

typedef unsigned short ushort_t;
typedef __attribute__((ext_vector_type(8))) short short8;
typedef __attribute__((ext_vector_type(8))) _Float16 half8;
typedef __attribute__((ext_vector_type(4))) float f32x4;
typedef __attribute__((ext_vector_type(16))) float f32x16;
typedef __attribute__((ext_vector_type(2))) unsigned uint2v;
typedef __attribute__((ext_vector_type(4))) unsigned uint4v;

#define LOG2E 1.44269504088896f

// async global->LDS, 16B per lane. LDS dest must be wave-uniform base + lane*16.
__device__ __forceinline__ void async16(const void* g, void* l) {
  __builtin_amdgcn_global_load_lds(
      (const __attribute__((address_space(1))) void*)g,
      (__attribute__((address_space(3))) void*)l, 16, 0, 0);
}

__device__ __forceinline__ ushort_t f2h(float f) {
  union { _Float16 h; ushort_t u; } c; c.h = (_Float16)f; return c.u;
}

__device__ __forceinline__ half8 u4h8(uint4v u) { union { uint4v a; half8 b; } c; c.a = u; return c.b; }

__device__ __forceinline__ f32x16 zero16() {
  f32x16 v;
  #pragma unroll
  for (int i = 0; i < 16; i++) v[i] = 0.f;
  return v;
}

// ------------- merged ingest: weight transpose AND activation cast, fp16 ----
// blocks 0..1023: transpose Wq/Wkv/Wo -> fp16 [N][K] (B^T layout)
// blocks 1024..5119: cast cur/hid fp32 -> fp16
__global__ __launch_bounds__(256) void prep_all(const float* __restrict__ cur,
                                                const float* __restrict__ hid,
                                                const float* __restrict__ Wq,
                                                const float* __restrict__ Wkv,
                                                const float* __restrict__ Wo,
                                                ushort_t* __restrict__ ch,
                                                ushort_t* __restrict__ hh,
                                                ushort_t* __restrict__ qT,
                                                ushort_t* __restrict__ kvT,
                                                ushort_t* __restrict__ oT) {
  __shared__ float tile[32][33];
  int bid = blockIdx.x;
  if (bid >= 1024) {
    // ---- activation cast path ----
    int i = (bid - 1024) * 256 + threadIdx.x;       // 0 .. 2*524288-1
    const float* src;
    ushort_t* dst;
    int j;
    if (i < 524288) { src = cur; dst = ch; j = i; }
    else            { src = hid; dst = hh; j = i - 524288; }
    const f32x4* s = (const f32x4*)src;
    f32x4 a = s[j * 2], b = s[j * 2 + 1];
    short8 o;
    #pragma unroll
    for (int k = 0; k < 4; k++) {
      o[k] = (short)f2h(a[k]);
      o[k + 4] = (short)f2h(b[k]);
    }
    ((short8*)dst)[j] = o;
    return;
  }
  // ---- weight transpose path ----
  const float* src; ushort_t* dh; int Nn, bx, by;
  const int K = 512;
  if (bid < 256)      { src = Wq;  dh = qT;  Nn = 512;  bx = (bid & 15) * 32; by = (bid >> 4) * 32; }
  else if (bid < 768) { int b = bid - 256; src = Wkv; dh = kvT; Nn = 1024; bx = (b & 31) * 32; by = (b >> 5) * 32; }
  else                { int b = bid - 768; src = Wo;  dh = oT;  Nn = 512;  bx = (b & 15) * 32; by = (b >> 4) * 32; }
  int tx = threadIdx.x & 31, ty = threadIdx.x >> 5;   // (32, 8)
  #pragma unroll
  for (int i = 0; i < 32; i += 8)
    tile[ty + i][tx] = src[(size_t)(by + ty + i) * Nn + bx + tx];
  __syncthreads();
  #pragma unroll
  for (int i = 0; i < 32; i += 8) {
    float v = tile[tx][ty + i];
    size_t idx = (size_t)(bx + ty + i) * K + by + tx;
    dh[idx] = f2h(v);
  }
}

// ---- fp16 GEMM body: C = A[M][K] @ B[Nn][K]^T, fp32 accumulate ----
// BM=64, BN=128, 4 waves (2x2); wave tile 32x64. T4 counted-vmcnt pipeline
// (stage t+1 -> vmcnt(3) -> barrier -> compute t -> lgkmcnt(0) -> barrier).
// T2 swizzle both-sides (verified 0-conflict in round 6): source chunk
// kc ^= (row>>1)&3, read chunk lq ^= (row>>1)&3; LDS dest linear for DMA.
// LDS 24.6 KB -> 6 blocks/CU resident.
template<int EPI>
__device__ __forceinline__ void gemm_body(const ushort_t* __restrict__ A,
                                          const ushort_t* __restrict__ B,
                                          ushort_t* __restrict__ o_16,
                                          ushort_t* __restrict__ o_vt,
                                          float* __restrict__ outf,
                                          int K, int ldo, int m0, int n0,
                                          ushort_t* lds) {
  constexpr int MT = 2, TN = 4;
  ushort_t* Ash = lds;            // [2][2048]
  ushort_t* Bsh = lds + 4096;     // [2][4096]
  const int tid = threadIdx.x;
  const int wave = tid >> 6, lane = tid & 63;
  const int wm = (wave >> 1) * 32, wn = (wave & 1) * 64;
  const int lrow = lane & 15, lq = lane >> 4;

  f32x4 acc[MT][TN];
  const f32x4 z = {0.f, 0.f, 0.f, 0.f};
  #pragma unroll
  for (int i = 0; i < MT; i++)
    #pragma unroll
    for (int j = 0; j < TN; j++) acc[i][j] = z;

  auto stage = [&](int k0, int d) {
    const int aoff = d * 2048, boff = d * 4096;
    {                                     // A tile: 64 rows x 4 chunks
      int r = tid >> 2, kc = tid & 3;
      int kcs = kc ^ ((r >> 1) & 3);      // pre-swizzled source chunk
      async16(&A[(size_t)(m0 + r) * K + k0 + kcs * 8], &Ash[aoff + tid * 8]);
    }
    #pragma unroll
    for (int i = 0; i < 2; i++) {         // B tile: 128 rows x 4 chunks
      int g = i * 256 + tid;
      int r = g >> 2, kc = g & 3;
      int kcs = kc ^ ((r >> 1) & 3);
      async16(&B[(size_t)(n0 + r) * K + k0 + kcs * 8], &Bsh[boff + g * 8]);
    }
  };

  stage(0, 0);
  int cur = 0;
  for (int k0 = 0; k0 < K; k0 += 32) {
    if (k0 + 32 < K) {
      stage(k0 + 32, cur ^ 1);   // 3 loads/thread, stay in flight across barrier
      asm volatile("s_waitcnt vmcnt(3)" ::: "memory");   // tile k0 landed
    } else {
      asm volatile("s_waitcnt vmcnt(0)" ::: "memory");
    }
    __builtin_amdgcn_s_barrier();

    const int ab = cur * 2048, bb = cur * 4096;
    half8 af[MT], bf[TN];
    #pragma unroll
    for (int t = 0; t < MT; t++) {
      int row = wm + t * 16 + lrow;
      af[t] = *(const half8*)&Ash[ab + row * 32 + (lq ^ ((row >> 1) & 3)) * 8];
    }
    #pragma unroll
    for (int t = 0; t < TN; t++) {
      int row = wn + t * 16 + lrow;
      bf[t] = *(const half8*)&Bsh[bb + row * 32 + (lq ^ ((row >> 1) & 3)) * 8];
    }
    #pragma unroll
    for (int ti = 0; ti < MT; ti++)
      #pragma unroll
      for (int tj = 0; tj < TN; tj++)
        acc[ti][tj] = __builtin_amdgcn_mfma_f32_16x16x32_f16(af[ti], bf[tj], acc[ti][tj], 0, 0, 0);

    if (k0 + 32 < K) {   // readers done before next iter's stage overwrites buf
      asm volatile("s_waitcnt lgkmcnt(0)" ::: "memory");
      __builtin_amdgcn_s_barrier();
    }
    cur ^= 1;
  }

  // epilogue
  #pragma unroll
  for (int ti = 0; ti < MT; ti++) {
    #pragma unroll
    for (int tj = 0; tj < TN; tj++) {
      int row0 = m0 + wm + ti * 16 + lq * 4;
      int col = n0 + wn + tj * 16 + lrow;
      #pragma unroll
      for (int r = 0; r < 4; r++) {
        int m = row0 + r;
        float fv = acc[ti][tj][r];
        if (EPI == 0) {
          // q-layout [B*H][N][D]
          size_t idx = (size_t)((m >> 10) * 8 + (col >> 6)) * 65536 + (m & 1023) * 64 + (col & 63);
          o_16[idx] = f2h(fv);
        } else if (EPI == 1) {
          if (col < 512) {   // k-layout
            size_t idx = (size_t)((m >> 10) * 8 + (col >> 6)) * 65536 + (m & 1023) * 64 + (col & 63);
            o_16[idx] = f2h(fv);
          } else {           // v^T layout [B*H][D][N]
            int cc = col - 512;
            o_vt[(size_t)(((m >> 10) * 8 + (cc >> 6)) * 64 + (cc & 63)) * 1024 + (m & 1023)] = f2h(fv);
          }
        } else {
          outf[(size_t)m * ldo + col] = fv;   // fp32 final output
        }
      }
    }
  }
}

// merged q+kv projection: 1536 blocks, XCD-bijective remap (1536 = 8*192).
__global__ __launch_bounds__(256) void gemm_qkv(const ushort_t* __restrict__ H,
                                                const ushort_t* __restrict__ WkvT,
                                                ushort_t* __restrict__ ko,
                                                ushort_t* __restrict__ vt,
                                                const ushort_t* __restrict__ C,
                                                const ushort_t* __restrict__ WqT,
                                                ushort_t* __restrict__ qo) {
  __shared__ __align__(16) ushort_t lds[12288];
  int bid = blockIdx.x;
  int w = (bid & 7) * 192 + (bid >> 3);      // contiguous work per XCD
  if (w < 1024) {
    int n0 = (w & 7) * 128, m0 = (w >> 3) * 64;
    gemm_body<1>(H, WkvT, ko, vt, (float*)nullptr, 512, 0, m0, n0, lds);
  } else {
    int ww = w - 1024;
    int n0 = (ww & 3) * 128, m0 = (ww >> 2) * 64;
    gemm_body<0>(C, WqT, qo, (ushort_t*)nullptr, (float*)nullptr, 512, 0, m0, n0, lds);
  }
}

// output projection: 512 blocks, XCD-bijective remap (512 = 8*64), fp32 out.
__global__ __launch_bounds__(256) void gemm_o(const ushort_t* __restrict__ A,
                                              const ushort_t* __restrict__ B,
                                              float* __restrict__ outf) {
  __shared__ __align__(16) ushort_t lds[12288];
  int bid = blockIdx.x;
  int w = (bid & 7) * 64 + (bid >> 3);
  int n0 = (w & 3) * 128, m0 = (w >> 2) * 64;
  gemm_body<2>(A, B, (ushort_t*)nullptr, (ushort_t*)nullptr, outf, 512, 512, m0, n0, lds);
}

// ---------------- flash attention: fp16, 32x32 core, counted-vmcnt ----------
// 512 blocks: bh = blk & 63 (all 8 q-tiles of a head share blk%8 -> one XCD).
// 4 waves x 32 q-rows. QK^T swapped (S^T via mfma32(K,Q)); in-register softmax;
// P via v_cvt_pkrtz_f16 + permlane32_swap; PV swapped (O^T via mfma32(V^T,P)).
// K/V staged via global_load_lds, pre-swizzled source (chunk ^= row&7).
// T4: stage(t+1); vmcnt(4); barrier; compute(t); lgkmcnt(0); barrier.
__global__ __launch_bounds__(256, 2) void flash_attn(const ushort_t* __restrict__ qb,
                                                     const ushort_t* __restrict__ kb,
                                                     const ushort_t* __restrict__ vtb,
                                                     ushort_t* __restrict__ ob) {
  __shared__ __align__(16) ushort_t Ksh[2][64 * 64];
  __shared__ __align__(16) ushort_t VTs[2][64 * 64];

  const int tid = threadIdx.x;
  const int wave = tid >> 6, lane = tid & 63;
  const int bh = blockIdx.x & 63, qt = blockIdx.x >> 6;
  const int l31 = lane & 31, hi = lane >> 5;

  const ushort_t* Q = qb + (size_t)bh * 65536;
  const ushort_t* Kp = kb + (size_t)bh * 65536;
  const ushort_t* VT = vtb + (size_t)bh * 65536;

  const int qrow0 = qt * 128 + wave * 32;

  // Q fragments (B-operand: col q = l31, contraction d = ds*16 + hi*8 + 0..7)
  half8 qf[4];
  #pragma unroll
  for (int ds = 0; ds < 4; ds++)
    qf[ds] = *(const half8*)&Q[(size_t)(qrow0 + l31) * 64 + ds * 16 + hi * 8];

  f32x16 oacc[2];                 // O^T: [dtile]; row d, col q = l31
  oacc[0] = zero16();
  oacc[1] = zero16();
  float m_i = -1e30f, l_i = 0.f;  // per q = qrow0 + l31 (replicated over hi)

  // swizzled-read offsets: phys chunk = (2*i + hi) ^ (l31 & 7); i = ds or ks
  const int r7 = l31 & 7;
  int pc[4];
  #pragma unroll
  for (int i = 0; i < 4; i++) pc[i] = (((2 * i + hi) ^ r7) << 3);
  const int ro0 = l31 * 64, ro1 = ro0 + 2048;   // rows l31 and 32+l31

  // stage kt-tile into buffer d: linear LDS dest, inverse-swizzled global src
  auto stage = [&](int kt, int d) {
    #pragma unroll
    for (int i = 0; i < 2; i++) {
      int g = i * 256 + tid, rw = g >> 3, ch = g & 7;
      int co = ((ch ^ (rw & 7)) << 3);           // swizzled source column
      int lofs = rw * 64 + (ch << 3);            // linear LDS offset
      async16(&Kp[(size_t)(kt * 64 + rw) * 64 + co], &Ksh[d][lofs]);
      async16(&VT[(size_t)rw * 1024 + kt * 64 + co], &VTs[d][lofs]);
    }
  };

  stage(0, 0);

  for (int kt = 0; kt < 16; kt++) {
    const int cur = kt & 1;
    if (kt < 15) {
      stage(kt + 1, cur ^ 1);     // 4 loads/thread, in flight across barrier
      asm volatile("s_waitcnt vmcnt(4)" ::: "memory");   // tile kt landed
    } else {
      asm volatile("s_waitcnt vmcnt(0)" ::: "memory");
    }
    __builtin_amdgcn_s_barrier();

    // ---- QK^T: sacc = S^T (rows k, cols q = l31) ----
    f32x16 sacc0 = zero16(), sacc1 = zero16();
    __builtin_amdgcn_s_setprio(1);
    #pragma unroll
    for (int ds = 0; ds < 4; ds++) {
      half8 k0 = *(const half8*)&Ksh[cur][ro0 + pc[ds]];
      half8 k1 = *(const half8*)&Ksh[cur][ro1 + pc[ds]];
      sacc0 = __builtin_amdgcn_mfma_f32_32x32x16_f16(k0, qf[ds], sacc0, 0, 0, 0);
      sacc1 = __builtin_amdgcn_mfma_f32_32x32x16_f16(k1, qf[ds], sacc1, 0, 0, 0);
    }
    __builtin_amdgcn_s_setprio(0);

    // ---- in-register online softmax (q = l31; reduce across hi-halves) ----
    float mx = -1e30f;
    #pragma unroll
    for (int r = 0; r < 16; r++) {
      mx = fmaxf(mx, sacc0[r]);
      mx = fmaxf(mx, sacc1[r]);
    }
    mx = fmaxf(mx, __shfl_xor(mx, 32));
    float mnew = fmaxf(m_i, mx);
    float mL = mnew * LOG2E;
    float alpha = exp2f(fmaf(m_i, LOG2E, -mL));
    float sum = 0.f;
    unsigned pw[16];
    #pragma unroll
    for (int j = 0; j < 8; j++) {
      float p0 = exp2f(fmaf(sacc0[2 * j], LOG2E, -mL));
      float p1 = exp2f(fmaf(sacc0[2 * j + 1], LOG2E, -mL));
      sum += p0 + p1;
      asm("v_cvt_pkrtz_f16_f32 %0, %1, %2" : "=v"(pw[j]) : "v"(p0), "v"(p1));
    }
    #pragma unroll
    for (int j = 0; j < 8; j++) {
      float p0 = exp2f(fmaf(sacc1[2 * j], LOG2E, -mL));
      float p1 = exp2f(fmaf(sacc1[2 * j + 1], LOG2E, -mL));
      sum += p0 + p1;
      asm("v_cvt_pkrtz_f16_f32 %0, %1, %2" : "=v"(pw[8 + j]) : "v"(p0), "v"(p1));
    }
    sum += __shfl_xor(sum, 32);
    l_i = fmaf(l_i, alpha, sum);
    m_i = mnew;
    #pragma unroll
    for (int r = 0; r < 16; r++) {
      oacc[0][r] *= alpha;
      oacc[1][r] *= alpha;
    }

    // ---- PV: oacc[dt] += mfma32(V^T-frag, P-frag) ----
    __builtin_amdgcn_s_setprio(1);
    #pragma unroll
    for (int ks = 0; ks < 4; ks++) {
      const int base = (ks >> 1) * 8 + (ks & 1) * 4;
      uint2v s0 = __builtin_amdgcn_permlane32_swap(pw[base + 0], pw[base + 2], false, false);
      uint2v s1 = __builtin_amdgcn_permlane32_swap(pw[base + 1], pw[base + 3], false, false);
      half8 pfrag = u4h8((uint4v){s0.x, s1.x, s0.y, s1.y});
      half8 vf0 = *(const half8*)&VTs[cur][ro0 + pc[ks]];
      half8 vf1 = *(const half8*)&VTs[cur][ro1 + pc[ks]];
      oacc[0] = __builtin_amdgcn_mfma_f32_32x32x16_f16(vf0, pfrag, oacc[0], 0, 0, 0);
      oacc[1] = __builtin_amdgcn_mfma_f32_32x32x16_f16(vf1, pfrag, oacc[1], 0, 0, 0);
    }
    __builtin_amdgcn_s_setprio(0);

    if (kt < 15) {   // readers done before next iter's stage overwrites buf
      asm volatile("s_waitcnt lgkmcnt(0)" ::: "memory");
      __builtin_amdgcn_s_barrier();
    }
  }

  // ---- epilogue: lane-local 1/l, fp16 uint2 stores ----
  const int b = bh >> 3, h = bh & 7;
  const int n = qrow0 + l31;
  float rinv = 1.f / l_i;
  #pragma unroll
  for (int dt = 0; dt < 2; dt++) {
    #pragma unroll
    for (int t = 0; t < 4; t++) {
      ushort_t hv[4];
      #pragma unroll
      for (int e = 0; e < 4; e++)
        hv[e] = f2h(oacc[dt][4 * t + e] * rinv);
      size_t idx = (size_t)(b * 1024 + n) * 512 + h * 64 + dt * 32 + t * 8 + hi * 4;
      *(uint2v*)&ob[idx] = (uint2v){(unsigned)hv[0] | ((unsigned)hv[1] << 16),
                                    (unsigned)hv[2] | ((unsigned)hv[3] << 16)};
    }
  }
}

// ---------------- launcher ----------------
extern "C" void kernel_launch(void* const* d_in, const int* in_sizes, int n_in,
                              void* d_out, int out_size, void* d_ws, size_t ws_size,
                              hipStream_t stream) {
  const float* cur = (const float*)d_in[0];   // [8,1024,512] fp32
  const float* hid = (const float*)d_in[1];   // [8,1024,512] fp32
  const float* Wq  = (const float*)d_in[2];   // [512,512]
  const float* Wkv = (const float*)d_in[3];   // [512,1024]
  const float* Wo  = (const float*)d_in[4];   // [512,512]

  ushort_t* ws = (ushort_t*)d_ws;
  ushort_t* C   = ws;                   // 4,194,304  (cur fp16; reused: attn out)
  ushort_t* H   = C + 4194304;          // 4,194,304  (hid fp16)
  ushort_t* ko  = H + 4194304;          // 4,194,304  (k, k-layout)
  ushort_t* vt  = ko + 4194304;         // 4,194,304  (v^T layout)
  ushort_t* qo  = vt + 4194304;         // 4,194,304  (q, q-layout)
  ushort_t* WqT = qo + 4194304;         // 262,144
  ushort_t* WkvT = WqT + 262144;        // 524,288
  ushort_t* WoT = WkvT + 524288;        // 262,144

  // merged ingest: weight transpose (blocks 0..1023) + activation cast (1024..5119)
  prep_all<<<5120, 256, 0, stream>>>(cur, hid, Wq, Wkv, Wo, C, H, WqT, WkvT, WoT);

  // merged kv + q projections: 1536 blocks, XCD-contiguous work
  gemm_qkv<<<1536, 256, 0, stream>>>(H, WkvT, ko, vt, C, WqT, qo);

  // attention: 512 blocks (head-major XCD grouping), 128 q-rows/block; out -> C
  flash_attn<<<512, 256, 0, stream>>>(qo, ko, vt, C);

  // output projection: 512 blocks -> fp32 d_out
  gemm_o<<<512, 256, 0, stream>>>(C, WoT, (float*)d_out);
}

// Round 8
// 166.084 us; speedup vs baseline: 1.3179x; 1.0236x over previous
//
#include <hip/hip_runtime.h>

typedef unsigned short ushort_t;
typedef __attribute__((ext_vector_type(8))) short short8;
typedef __attribute__((ext_vector_type(8))) _Float16 half8;
typedef __attribute__((ext_vector_type(4))) float f32x4;
typedef __attribute__((ext_vector_type(16))) float f32x16;
typedef __attribute__((ext_vector_type(2))) unsigned uint2v;
typedef __attribute__((ext_vector_type(4))) unsigned uint4v;

#define LOG2E 1.44269504088896f

// async global->LDS, 16B per lane. LDS dest must be wave-uniform base + lane*16.
__device__ __forceinline__ void async16(const void* g, void* l) {
  __builtin_amdgcn_global_load_lds(
      (const __attribute__((address_space(1))) void*)g,
      (__attribute__((address_space(3))) void*)l, 16, 0, 0);
}

__device__ __forceinline__ ushort_t f2h(float f) {
  union { _Float16 h; ushort_t u; } c; c.h = (_Float16)f; return c.u;
}

__device__ __forceinline__ half8 u4h8(uint4v u) { union { uint4v a; half8 b; } c; c.a = u; return c.b; }

__device__ __forceinline__ f32x16 zero16() {
  f32x16 v;
  #pragma unroll
  for (int i = 0; i < 16; i++) v[i] = 0.f;
  return v;
}

// ------------- merged ingest: weight transpose AND activation cast, fp16 ----
// blocks 0..1023: transpose Wq/Wkv/Wo -> fp16 [N][K] (B^T layout)
// blocks 1024..5119: cast cur/hid fp32 -> fp16
__global__ __launch_bounds__(256) void prep_all(const float* __restrict__ cur,
                                                const float* __restrict__ hid,
                                                const float* __restrict__ Wq,
                                                const float* __restrict__ Wkv,
                                                const float* __restrict__ Wo,
                                                ushort_t* __restrict__ ch,
                                                ushort_t* __restrict__ hh,
                                                ushort_t* __restrict__ qT,
                                                ushort_t* __restrict__ kvT,
                                                ushort_t* __restrict__ oT) {
  __shared__ float tile[32][33];
  int bid = blockIdx.x;
  if (bid >= 1024) {
    // ---- activation cast path ----
    int i = (bid - 1024) * 256 + threadIdx.x;       // 0 .. 2*524288-1
    const float* src;
    ushort_t* dst;
    int j;
    if (i < 524288) { src = cur; dst = ch; j = i; }
    else            { src = hid; dst = hh; j = i - 524288; }
    const f32x4* s = (const f32x4*)src;
    f32x4 a = s[j * 2], b = s[j * 2 + 1];
    short8 o;
    #pragma unroll
    for (int k = 0; k < 4; k++) {
      o[k] = (short)f2h(a[k]);
      o[k + 4] = (short)f2h(b[k]);
    }
    ((short8*)dst)[j] = o;
    return;
  }
  // ---- weight transpose path ----
  const float* src; ushort_t* dh; int Nn, bx, by;
  const int K = 512;
  if (bid < 256)      { src = Wq;  dh = qT;  Nn = 512;  bx = (bid & 15) * 32; by = (bid >> 4) * 32; }
  else if (bid < 768) { int b = bid - 256; src = Wkv; dh = kvT; Nn = 1024; bx = (b & 31) * 32; by = (b >> 5) * 32; }
  else                { int b = bid - 768; src = Wo;  dh = oT;  Nn = 512;  bx = (b & 15) * 32; by = (b >> 4) * 32; }
  int tx = threadIdx.x & 31, ty = threadIdx.x >> 5;   // (32, 8)
  #pragma unroll
  for (int i = 0; i < 32; i += 8)
    tile[ty + i][tx] = src[(size_t)(by + ty + i) * Nn + bx + tx];
  __syncthreads();
  #pragma unroll
  for (int i = 0; i < 32; i += 8) {
    float v = tile[tx][ty + i];
    size_t idx = (size_t)(bx + ty + i) * K + by + tx;
    dh[idx] = f2h(v);
  }
}

// ---- fp16 GEMM body: C = A[M][K] @ B[Nn][K]^T, fp32 accumulate ----
// Wave tile (MT*16)x(TN*16); block (MT*32)x(TN*32); 4 waves (2x2).
// Triple-buffered LDS, depth-2 prefetch (T3/T4):
//   stage(t+2) -> vmcnt(2*LPS) [t landed; t+1,t+2 in flight] -> barrier ->
//   compute(t) -> lgkmcnt(0) -> barrier.
// T2 swizzle both-sides (0-conflict verified r6): source chunk kc ^= (row>>1)&3,
// read chunk lq ^= (row>>1)&3; LDS dest stays linear for global_load_lds.
template<int EPI, int MT, int TN>
__device__ __forceinline__ void gemm_body(const ushort_t* __restrict__ A,
                                          const ushort_t* __restrict__ B,
                                          ushort_t* __restrict__ o_16,
                                          ushort_t* __restrict__ o_vt,
                                          float* __restrict__ outf,
                                          int K, int ldo, int m0, int n0,
                                          ushort_t* lds) {
  constexpr int BM = MT * 32;
  constexpr int BN = TN * 32;
  constexpr int ASZ = BM * 32;       // halves per A buffer
  constexpr int BSZ = BN * 32;       // halves per B buffer
  constexpr int LPS = (MT + TN) / 2; // async16 per thread per stage
  ushort_t* Ash = lds;               // [3][ASZ]
  ushort_t* Bsh = lds + 3 * ASZ;     // [3][BSZ]
  const int tid = threadIdx.x;
  const int wave = tid >> 6, lane = tid & 63;
  const int wm = (wave >> 1) * (MT * 16), wn = (wave & 1) * (TN * 16);
  const int lrow = lane & 15, lq = lane >> 4;

  f32x4 acc[MT][TN];
  const f32x4 z = {0.f, 0.f, 0.f, 0.f};
  #pragma unroll
  for (int i = 0; i < MT; i++)
    #pragma unroll
    for (int j = 0; j < TN; j++) acc[i][j] = z;

  auto stage = [&](int t, int d) {
    const int k0 = t * 32;
    const int aoff = d * ASZ, boff = d * BSZ;
    #pragma unroll
    for (int i = 0; i < MT / 2; i++) {       // A tile: BM rows x 4 chunks
      int g = i * 256 + tid;
      int r = g >> 2, kc = g & 3;
      int kcs = kc ^ ((r >> 1) & 3);         // pre-swizzled source chunk
      async16(&A[(size_t)(m0 + r) * K + k0 + kcs * 8], &Ash[aoff + g * 8]);
    }
    #pragma unroll
    for (int i = 0; i < TN / 2; i++) {       // B tile: BN rows x 4 chunks
      int g = i * 256 + tid;
      int r = g >> 2, kc = g & 3;
      int kcs = kc ^ ((r >> 1) & 3);
      async16(&B[(size_t)(n0 + r) * K + k0 + kcs * 8], &Bsh[boff + g * 8]);
    }
  };

  const int nt = K >> 5;                     // 16 K-tiles
  stage(0, 0);
  stage(1, 1);
  for (int t = 0; t < nt; t++) {
    if (t + 2 < nt) stage(t + 2, (t + 2) % 3);
    // wait: stage(t) landed; up to 2 stages (2*LPS loads) stay in flight
    if (t + 2 < nt) {
      if constexpr (LPS == 4) asm volatile("s_waitcnt vmcnt(8)" ::: "memory");
      else                    asm volatile("s_waitcnt vmcnt(6)" ::: "memory");
    } else if (t + 1 < nt) {
      if constexpr (LPS == 4) asm volatile("s_waitcnt vmcnt(4)" ::: "memory");
      else                    asm volatile("s_waitcnt vmcnt(3)" ::: "memory");
    } else {
      asm volatile("s_waitcnt vmcnt(0)" ::: "memory");
    }
    __builtin_amdgcn_s_barrier();

    const int d = t % 3;
    const int ab = d * ASZ, bb = d * BSZ;
    half8 af[MT], bf[TN];
    #pragma unroll
    for (int ti = 0; ti < MT; ti++) {
      int row = wm + ti * 16 + lrow;
      af[ti] = *(const half8*)&Ash[ab + row * 32 + (lq ^ ((row >> 1) & 3)) * 8];
    }
    #pragma unroll
    for (int tj = 0; tj < TN; tj++) {
      int row = wn + tj * 16 + lrow;
      bf[tj] = *(const half8*)&Bsh[bb + row * 32 + (lq ^ ((row >> 1) & 3)) * 8];
    }
    #pragma unroll
    for (int ti = 0; ti < MT; ti++)
      #pragma unroll
      for (int tj = 0; tj < TN; tj++)
        acc[ti][tj] = __builtin_amdgcn_mfma_f32_16x16x32_f16(af[ti], bf[tj], acc[ti][tj], 0, 0, 0);

    if (t + 1 < nt) {   // readers done before a later stage overwrites this buf
      asm volatile("s_waitcnt lgkmcnt(0)" ::: "memory");
      __builtin_amdgcn_s_barrier();
    }
  }

  // epilogue
  #pragma unroll
  for (int ti = 0; ti < MT; ti++) {
    #pragma unroll
    for (int tj = 0; tj < TN; tj++) {
      int row0 = m0 + wm + ti * 16 + lq * 4;
      int col = n0 + wn + tj * 16 + lrow;
      #pragma unroll
      for (int r = 0; r < 4; r++) {
        int m = row0 + r;
        float fv = acc[ti][tj][r];
        if (EPI == 0) {
          // q-layout [B*H][N][D]
          size_t idx = (size_t)((m >> 10) * 8 + (col >> 6)) * 65536 + (m & 1023) * 64 + (col & 63);
          o_16[idx] = f2h(fv);
        } else if (EPI == 1) {
          if (col < 512) {   // k-layout
            size_t idx = (size_t)((m >> 10) * 8 + (col >> 6)) * 65536 + (m & 1023) * 64 + (col & 63);
            o_16[idx] = f2h(fv);
          } else {           // v^T layout [B*H][D][N]
            int cc = col - 512;
            o_vt[(size_t)(((m >> 10) * 8 + (cc >> 6)) * 64 + (cc & 63)) * 1024 + (m & 1023)] = f2h(fv);
          }
        } else {
          outf[(size_t)m * ldo + col] = fv;   // fp32 final output
        }
      }
    }
  }
}

// merged q+kv projection: 768 blocks (128x128 tiles), XCD remap (768 = 8*96).
// w < 512 -> kv (grid 8x64), w >= 512 -> q (grid 4x64). Block-uniform branch.
__global__ __launch_bounds__(256) void gemm_qkv(const ushort_t* __restrict__ H,
                                                const ushort_t* __restrict__ WkvT,
                                                ushort_t* __restrict__ ko,
                                                ushort_t* __restrict__ vt,
                                                const ushort_t* __restrict__ C,
                                                const ushort_t* __restrict__ WqT,
                                                ushort_t* __restrict__ qo) {
  __shared__ __align__(16) ushort_t lds[24576];   // 48 KB: 3 x (8KB A + 8KB B)
  int bid = blockIdx.x;
  int w = (bid & 7) * 96 + (bid >> 3);       // contiguous work per XCD
  if (w < 512) {
    int n0 = (w & 7) * 128, m0 = (w >> 3) * 128;
    gemm_body<1, 4, 4>(H, WkvT, ko, vt, (float*)nullptr, 512, 0, m0, n0, lds);
  } else {
    int ww = w - 512;
    int n0 = (ww & 3) * 128, m0 = (ww >> 2) * 128;
    gemm_body<0, 4, 4>(C, WqT, qo, (ushort_t*)nullptr, (float*)nullptr, 512, 0, m0, n0, lds);
  }
}

// output projection: 512 blocks (64x128 tiles), XCD remap (512 = 8*64), fp32 out.
__global__ __launch_bounds__(256) void gemm_o(const ushort_t* __restrict__ A,
                                              const ushort_t* __restrict__ B,
                                              float* __restrict__ outf) {
  __shared__ __align__(16) ushort_t lds[18432];   // 36 KB: 3 x (4KB A + 8KB B)
  int bid = blockIdx.x;
  int w = (bid & 7) * 64 + (bid >> 3);
  int n0 = (w & 3) * 128, m0 = (w >> 2) * 64;
  gemm_body<2, 2, 4>(A, B, (ushort_t*)nullptr, (ushort_t*)nullptr, outf, 512, 512, m0, n0, lds);
}

// ---------------- flash attention: fp16, 32x32 core, counted-vmcnt ----------
// 512 blocks: bh = blk & 63 (all 8 q-tiles of a head share blk%8 -> one XCD).
// 4 waves x 32 q-rows. QK^T swapped (S^T via mfma32(K,Q)); in-register softmax;
// P via v_cvt_pkrtz_f16 + permlane32_swap; PV swapped (O^T via mfma32(V^T,P)).
// K/V staged via global_load_lds, pre-swizzled source (chunk ^= row&7).
// T4: stage(t+1); vmcnt(4); barrier; compute(t); lgkmcnt(0); barrier.
__global__ __launch_bounds__(256, 2) void flash_attn(const ushort_t* __restrict__ qb,
                                                     const ushort_t* __restrict__ kb,
                                                     const ushort_t* __restrict__ vtb,
                                                     ushort_t* __restrict__ ob) {
  __shared__ __align__(16) ushort_t Ksh[2][64 * 64];
  __shared__ __align__(16) ushort_t VTs[2][64 * 64];

  const int tid = threadIdx.x;
  const int wave = tid >> 6, lane = tid & 63;
  const int bh = blockIdx.x & 63, qt = blockIdx.x >> 6;
  const int l31 = lane & 31, hi = lane >> 5;

  const ushort_t* Q = qb + (size_t)bh * 65536;
  const ushort_t* Kp = kb + (size_t)bh * 65536;
  const ushort_t* VT = vtb + (size_t)bh * 65536;

  const int qrow0 = qt * 128 + wave * 32;

  // Q fragments (B-operand: col q = l31, contraction d = ds*16 + hi*8 + 0..7)
  half8 qf[4];
  #pragma unroll
  for (int ds = 0; ds < 4; ds++)
    qf[ds] = *(const half8*)&Q[(size_t)(qrow0 + l31) * 64 + ds * 16 + hi * 8];

  f32x16 oacc[2];                 // O^T: [dtile]; row d, col q = l31
  oacc[0] = zero16();
  oacc[1] = zero16();
  float m_i = -1e30f, l_i = 0.f;  // per q = qrow0 + l31 (replicated over hi)

  // swizzled-read offsets: phys chunk = (2*i + hi) ^ (l31 & 7); i = ds or ks
  const int r7 = l31 & 7;
  int pc[4];
  #pragma unroll
  for (int i = 0; i < 4; i++) pc[i] = (((2 * i + hi) ^ r7) << 3);
  const int ro0 = l31 * 64, ro1 = ro0 + 2048;   // rows l31 and 32+l31

  // stage kt-tile into buffer d: linear LDS dest, inverse-swizzled global src
  auto stage = [&](int kt, int d) {
    #pragma unroll
    for (int i = 0; i < 2; i++) {
      int g = i * 256 + tid, rw = g >> 3, ch = g & 7;
      int co = ((ch ^ (rw & 7)) << 3);           // swizzled source column
      int lofs = rw * 64 + (ch << 3);            // linear LDS offset
      async16(&Kp[(size_t)(kt * 64 + rw) * 64 + co], &Ksh[d][lofs]);
      async16(&VT[(size_t)rw * 1024 + kt * 64 + co], &VTs[d][lofs]);
    }
  };

  stage(0, 0);

  for (int kt = 0; kt < 16; kt++) {
    const int cur = kt & 1;
    if (kt < 15) {
      stage(kt + 1, cur ^ 1);     // 4 loads/thread, in flight across barrier
      asm volatile("s_waitcnt vmcnt(4)" ::: "memory");   // tile kt landed
    } else {
      asm volatile("s_waitcnt vmcnt(0)" ::: "memory");
    }
    __builtin_amdgcn_s_barrier();

    // ---- QK^T: sacc = S^T (rows k, cols q = l31) ----
    f32x16 sacc0 = zero16(), sacc1 = zero16();
    __builtin_amdgcn_s_setprio(1);
    #pragma unroll
    for (int ds = 0; ds < 4; ds++) {
      half8 k0 = *(const half8*)&Ksh[cur][ro0 + pc[ds]];
      half8 k1 = *(const half8*)&Ksh[cur][ro1 + pc[ds]];
      sacc0 = __builtin_amdgcn_mfma_f32_32x32x16_f16(k0, qf[ds], sacc0, 0, 0, 0);
      sacc1 = __builtin_amdgcn_mfma_f32_32x32x16_f16(k1, qf[ds], sacc1, 0, 0, 0);
    }
    __builtin_amdgcn_s_setprio(0);

    // ---- in-register online softmax (q = l31; reduce across hi-halves) ----
    float mx = -1e30f;
    #pragma unroll
    for (int r = 0; r < 16; r++) {
      mx = fmaxf(mx, sacc0[r]);
      mx = fmaxf(mx, sacc1[r]);
    }
    mx = fmaxf(mx, __shfl_xor(mx, 32));
    float mnew = fmaxf(m_i, mx);
    float mL = mnew * LOG2E;
    float alpha = exp2f(fmaf(m_i, LOG2E, -mL));
    float sum = 0.f;
    unsigned pw[16];
    #pragma unroll
    for (int j = 0; j < 8; j++) {
      float p0 = exp2f(fmaf(sacc0[2 * j], LOG2E, -mL));
      float p1 = exp2f(fmaf(sacc0[2 * j + 1], LOG2E, -mL));
      sum += p0 + p1;
      asm("v_cvt_pkrtz_f16_f32 %0, %1, %2" : "=v"(pw[j]) : "v"(p0), "v"(p1));
    }
    #pragma unroll
    for (int j = 0; j < 8; j++) {
      float p0 = exp2f(fmaf(sacc1[2 * j], LOG2E, -mL));
      float p1 = exp2f(fmaf(sacc1[2 * j + 1], LOG2E, -mL));
      sum += p0 + p1;
      asm("v_cvt_pkrtz_f16_f32 %0, %1, %2" : "=v"(pw[8 + j]) : "v"(p0), "v"(p1));
    }
    sum += __shfl_xor(sum, 32);
    l_i = fmaf(l_i, alpha, sum);
    m_i = mnew;
    #pragma unroll
    for (int r = 0; r < 16; r++) {
      oacc[0][r] *= alpha;
      oacc[1][r] *= alpha;
    }

    // ---- PV: oacc[dt] += mfma32(V^T-frag, P-frag) ----
    __builtin_amdgcn_s_setprio(1);
    #pragma unroll
    for (int ks = 0; ks < 4; ks++) {
      const int base = (ks >> 1) * 8 + (ks & 1) * 4;
      uint2v s0 = __builtin_amdgcn_permlane32_swap(pw[base + 0], pw[base + 2], false, false);
      uint2v s1 = __builtin_amdgcn_permlane32_swap(pw[base + 1], pw[base + 3], false, false);
      half8 pfrag = u4h8((uint4v){s0.x, s1.x, s0.y, s1.y});
      half8 vf0 = *(const half8*)&VTs[cur][ro0 + pc[ks]];
      half8 vf1 = *(const half8*)&VTs[cur][ro1 + pc[ks]];
      oacc[0] = __builtin_amdgcn_mfma_f32_32x32x16_f16(vf0, pfrag, oacc[0], 0, 0, 0);
      oacc[1] = __builtin_amdgcn_mfma_f32_32x32x16_f16(vf1, pfrag, oacc[1], 0, 0, 0);
    }
    __builtin_amdgcn_s_setprio(0);

    if (kt < 15) {   // readers done before next iter's stage overwrites buf
      asm volatile("s_waitcnt lgkmcnt(0)" ::: "memory");
      __builtin_amdgcn_s_barrier();
    }
  }

  // ---- epilogue: lane-local 1/l, fp16 uint2 stores ----
  const int b = bh >> 3, h = bh & 7;
  const int n = qrow0 + l31;
  float rinv = 1.f / l_i;
  #pragma unroll
  for (int dt = 0; dt < 2; dt++) {
    #pragma unroll
    for (int t = 0; t < 4; t++) {
      ushort_t hv[4];
      #pragma unroll
      for (int e = 0; e < 4; e++)
        hv[e] = f2h(oacc[dt][4 * t + e] * rinv);
      size_t idx = (size_t)(b * 1024 + n) * 512 + h * 64 + dt * 32 + t * 8 + hi * 4;
      *(uint2v*)&ob[idx] = (uint2v){(unsigned)hv[0] | ((unsigned)hv[1] << 16),
                                    (unsigned)hv[2] | ((unsigned)hv[3] << 16)};
    }
  }
}

// ---------------- launcher ----------------
extern "C" void kernel_launch(void* const* d_in, const int* in_sizes, int n_in,
                              void* d_out, int out_size, void* d_ws, size_t ws_size,
                              hipStream_t stream) {
  const float* cur = (const float*)d_in[0];   // [8,1024,512] fp32
  const float* hid = (const float*)d_in[1];   // [8,1024,512] fp32
  const float* Wq  = (const float*)d_in[2];   // [512,512]
  const float* Wkv = (const float*)d_in[3];   // [512,1024]
  const float* Wo  = (const float*)d_in[4];   // [512,512]

  ushort_t* ws = (ushort_t*)d_ws;
  ushort_t* C   = ws;                   // 4,194,304  (cur fp16; reused: attn out)
  ushort_t* H   = C + 4194304;          // 4,194,304  (hid fp16)
  ushort_t* ko  = H + 4194304;          // 4,194,304  (k, k-layout)
  ushort_t* vt  = ko + 4194304;         // 4,194,304  (v^T layout)
  ushort_t* qo  = vt + 4194304;         // 4,194,304  (q, q-layout)
  ushort_t* WqT = qo + 4194304;         // 262,144
  ushort_t* WkvT = WqT + 262144;        // 524,288
  ushort_t* WoT = WkvT + 524288;        // 262,144

  // merged ingest: weight transpose (blocks 0..1023) + activation cast (1024..5119)
  prep_all<<<5120, 256, 0, stream>>>(cur, hid, Wq, Wkv, Wo, C, H, WqT, WkvT, WoT);

  // merged kv + q projections: 768 blocks (128x128 tiles), XCD-contiguous work
  gemm_qkv<<<768, 256, 0, stream>>>(H, WkvT, ko, vt, C, WqT, qo);

  // attention: 512 blocks (head-major XCD grouping), 128 q-rows/block; out -> C
  flash_attn<<<512, 256, 0, stream>>>(qo, ko, vt, C);

  // output projection: 512 blocks -> fp32 d_out
  gemm_o<<<512, 256, 0, stream>>>(C, WoT, (float*)d_out);
}

// Round 10
// 165.879 us; speedup vs baseline: 1.3195x; 1.0012x over previous
//
#include <hip/hip_runtime.h>

typedef unsigned short ushort_t;
typedef __attribute__((ext_vector_type(8))) short short8;
typedef __attribute__((ext_vector_type(8))) _Float16 half8;
typedef __attribute__((ext_vector_type(4))) float f32x4;
typedef __attribute__((ext_vector_type(16))) float f32x16;
typedef __attribute__((ext_vector_type(2))) unsigned uint2v;
typedef __attribute__((ext_vector_type(4))) unsigned uint4v;

#define LOG2E 1.44269504088896f

// async global->LDS, 16B per lane. LDS dest must be wave-uniform base + lane*16.
__device__ __forceinline__ void async16(const void* g, void* l) {
  __builtin_amdgcn_global_load_lds(
      (const __attribute__((address_space(1))) void*)g,
      (__attribute__((address_space(3))) void*)l, 16, 0, 0);
}

__device__ __forceinline__ ushort_t f2h(float f) {
  union { _Float16 h; ushort_t u; } c; c.h = (_Float16)f; return c.u;
}

__device__ __forceinline__ half8 u4h8(uint4v u) { union { uint4v a; half8 b; } c; c.a = u; return c.b; }

__device__ __forceinline__ f32x16 zero16() {
  f32x16 v;
  #pragma unroll
  for (int i = 0; i < 16; i++) v[i] = 0.f;
  return v;
}

// ------------- prep: weight transpose+cast only (activations fused into GEMM) --
// 1024 blocks: transpose Wq/Wkv/Wo -> fp16 [N][K] (B^T layout)
__global__ __launch_bounds__(256) void prep_w(const float* __restrict__ Wq,
                                              const float* __restrict__ Wkv,
                                              const float* __restrict__ Wo,
                                              ushort_t* __restrict__ qT,
                                              ushort_t* __restrict__ kvT,
                                              ushort_t* __restrict__ oT) {
  __shared__ float tile[32][33];
  int bid = blockIdx.x;
  const float* src; ushort_t* dh; int Nn, bx, by;
  const int K = 512;
  if (bid < 256)      { src = Wq;  dh = qT;  Nn = 512;  bx = (bid & 15) * 32; by = (bid >> 4) * 32; }
  else if (bid < 768) { int b = bid - 256; src = Wkv; dh = kvT; Nn = 1024; bx = (b & 31) * 32; by = (b >> 5) * 32; }
  else                { int b = bid - 768; src = Wo;  dh = oT;  Nn = 512;  bx = (b & 15) * 32; by = (b >> 4) * 32; }
  int tx = threadIdx.x & 31, ty = threadIdx.x >> 5;   // (32, 8)
  #pragma unroll
  for (int i = 0; i < 32; i += 8)
    tile[ty + i][tx] = src[(size_t)(by + ty + i) * Nn + bx + tx];
  __syncthreads();
  #pragma unroll
  for (int i = 0; i < 32; i += 8) {
    float v = tile[tx][ty + i];
    size_t idx = (size_t)(bx + ty + i) * K + by + tx;
    dh[idx] = f2h(v);
  }
}

// ---- fused-cast GEMM body: C = cast16(A32)[M][K] @ B16[Nn][K]^T ----
// BM=BN=128 (MT=TN=4), 4 waves (2x2), wave tile 64x64.
// A: fp32 source, reg-staged (T14 split: loads issued at top of iter t,
//    RTN-cast + ds_write after compute under vmcnt(2)) -> LDS image identical
//    to the DMA path (source-swizzled chunks, linear dest).
// B: fp16 source via global_load_lds, counted vmcnt.
// Schedule/iter: [loadA(t+1); dmaB(t+1)] vmcnt(6) barrier compute(t)
//                vmcnt(2) writeA(t+1) lgkmcnt(0) barrier.
template<int EPI>
__device__ __forceinline__ void gemm_cast_body(const float* __restrict__ A32,
                                               const ushort_t* __restrict__ B,
                                               ushort_t* __restrict__ o_16,
                                               ushort_t* __restrict__ o_vt,
                                               int K, int m0, int n0,
                                               ushort_t* lds) {
  constexpr int MT = 4, TN = 4;
  constexpr int ASZ = 128 * 32;      // halves per A buffer
  constexpr int BSZ = 128 * 32;      // halves per B buffer
  ushort_t* Ash = lds;               // [2][ASZ]
  ushort_t* Bsh = lds + 2 * ASZ;     // [2][BSZ]
  const int tid = threadIdx.x;
  const int wave = tid >> 6, lane = tid & 63;
  const int wm = (wave >> 1) * 64, wn = (wave & 1) * 64;
  const int lrow = lane & 15, lq = lane >> 4;

  f32x4 acc[MT][TN];
  const f32x4 z = {0.f, 0.f, 0.f, 0.f};
  #pragma unroll
  for (int i = 0; i < MT; i++)
    #pragma unroll
    for (int j = 0; j < TN; j++) acc[i][j] = z;

  f32x4 ar[4];   // in-flight A tile (2 chunk-slots x 2 float4)

  auto loadA = [&](int t) {
    const int k0 = t * 32;
    #pragma unroll
    for (int i = 0; i < 2; i++) {
      int g = i * 256 + tid, r = g >> 2, kc = g & 3;
      int kcs = kc ^ ((r >> 1) & 3);           // pre-swizzled source chunk
      const f32x4* p = (const f32x4*)&A32[(size_t)(m0 + r) * K + k0 + kcs * 8];
      ar[2 * i] = p[0];
      ar[2 * i + 1] = p[1];
    }
  };
  auto writeA = [&](int d) {
    #pragma unroll
    for (int i = 0; i < 2; i++) {
      int g = i * 256 + tid;
      short8 o;
      #pragma unroll
      for (int e = 0; e < 4; e++) {
        o[e] = (short)f2h(ar[2 * i][e]);
        o[e + 4] = (short)f2h(ar[2 * i + 1][e]);
      }
      *(short8*)&Ash[d * ASZ + g * 8] = o;     // linear dest (matches DMA image)
    }
  };
  auto stageB = [&](int t, int d) {
    const int k0 = t * 32;
    #pragma unroll
    for (int i = 0; i < 2; i++) {
      int g = i * 256 + tid, r = g >> 2, kc = g & 3;
      int kcs = kc ^ ((r >> 1) & 3);
      async16(&B[(size_t)(n0 + r) * K + k0 + kcs * 8], &Bsh[d * BSZ + g * 8]);
    }
  };

  // prologue: tile 0 staged (A regs -> LDS; B DMA in flight)
  loadA(0);
  stageB(0, 0);
  asm volatile("s_waitcnt vmcnt(2)" ::: "memory");   // A(0) regs landed
  writeA(0);
  asm volatile("s_waitcnt lgkmcnt(0)" ::: "memory");

  const int nt = K >> 5;
  for (int t = 0; t < nt; t++) {
    const int cur = t & 1;
    if (t + 1 < nt) {
      loadA(t + 1);            // A first (so vmcnt(2) below targets it)
      stageB(t + 1, cur ^ 1);
      asm volatile("s_waitcnt vmcnt(6)" ::: "memory");   // B(t) landed
    } else {
      asm volatile("s_waitcnt vmcnt(0)" ::: "memory");
    }
    __builtin_amdgcn_s_barrier();   // tile t fully visible to all waves

    const int ab = cur * ASZ, bb = cur * BSZ;
    half8 af[MT], bf[TN];
    #pragma unroll
    for (int ti = 0; ti < MT; ti++) {
      int row = wm + ti * 16 + lrow;
      af[ti] = *(const half8*)&Ash[ab + row * 32 + (lq ^ ((row >> 1) & 3)) * 8];
    }
    #pragma unroll
    for (int tj = 0; tj < TN; tj++) {
      int row = wn + tj * 16 + lrow;
      bf[tj] = *(const half8*)&Bsh[bb + row * 32 + (lq ^ ((row >> 1) & 3)) * 8];
    }
    #pragma unroll
    for (int ti = 0; ti < MT; ti++)
      #pragma unroll
      for (int tj = 0; tj < TN; tj++)
        acc[ti][tj] = __builtin_amdgcn_mfma_f32_16x16x32_f16(af[ti], bf[tj], acc[ti][tj], 0, 0, 0);

    if (t + 1 < nt) {
      asm volatile("s_waitcnt vmcnt(2)" ::: "memory");   // A(t+1) regs landed
      writeA(cur ^ 1);
      asm volatile("s_waitcnt lgkmcnt(0)" ::: "memory"); // reads+writes done
      __builtin_amdgcn_s_barrier();                      // release buffer cur
    }
  }

  // epilogue
  #pragma unroll
  for (int ti = 0; ti < MT; ti++) {
    #pragma unroll
    for (int tj = 0; tj < TN; tj++) {
      int row0 = m0 + wm + ti * 16 + lq * 4;
      int col = n0 + wn + tj * 16 + lrow;
      #pragma unroll
      for (int r = 0; r < 4; r++) {
        int m = row0 + r;
        float fv = acc[ti][tj][r];
        if (EPI == 0) {
          // q-layout [B*H][N][D]
          size_t idx = (size_t)((m >> 10) * 8 + (col >> 6)) * 65536 + (m & 1023) * 64 + (col & 63);
          o_16[idx] = f2h(fv);
        } else {
          if (col < 512) {   // k-layout
            size_t idx = (size_t)((m >> 10) * 8 + (col >> 6)) * 65536 + (m & 1023) * 64 + (col & 63);
            o_16[idx] = f2h(fv);
          } else {           // v^T layout [B*H][D][N]
            int cc = col - 512;
            o_vt[(size_t)(((m >> 10) * 8 + (cc >> 6)) * 64 + (cc & 63)) * 1024 + (m & 1023)] = f2h(fv);
          }
        }
      }
    }
  }
}

// merged q+kv projection with fused fp32->fp16 A-cast: 768 blocks,
// XCD remap (768 = 8*96). w < 512 -> kv (8x64), w >= 512 -> q (4x64).
__global__ __launch_bounds__(256) void gemm_qkv(const float* __restrict__ hid,
                                                const ushort_t* __restrict__ WkvT,
                                                ushort_t* __restrict__ ko,
                                                ushort_t* __restrict__ vt,
                                                const float* __restrict__ cur,
                                                const ushort_t* __restrict__ WqT,
                                                ushort_t* __restrict__ qo) {
  __shared__ __align__(16) ushort_t lds[16384];   // 32 KB: 2 x (8KB A + 8KB B)
  int bid = blockIdx.x;
  int w = (bid & 7) * 96 + (bid >> 3);       // contiguous work per XCD
  if (w < 512) {
    int n0 = (w & 7) * 128, m0 = (w >> 3) * 128;
    gemm_cast_body<1>(hid, WkvT, ko, vt, 512, m0, n0, lds);
  } else {
    int ww = w - 512;
    int n0 = (ww & 3) * 128, m0 = (ww >> 2) * 128;
    gemm_cast_body<0>(cur, WqT, qo, (ushort_t*)nullptr, 512, m0, n0, lds);
  }
}

// ---- fp16 GEMM body (A already fp16): r8 triple-buffer depth-2 (unchanged) ----
__device__ __forceinline__ void gemm_o_body(const ushort_t* __restrict__ A,
                                            const ushort_t* __restrict__ B,
                                            float* __restrict__ outf,
                                            int K, int ldo, int m0, int n0,
                                            ushort_t* lds) {
  constexpr int MT = 2, TN = 4;
  constexpr int ASZ = 64 * 32;
  constexpr int BSZ = 128 * 32;
  ushort_t* Ash = lds;               // [3][ASZ]
  ushort_t* Bsh = lds + 3 * ASZ;     // [3][BSZ]
  const int tid = threadIdx.x;
  const int wave = tid >> 6, lane = tid & 63;
  const int wm = (wave >> 1) * 32, wn = (wave & 1) * 64;
  const int lrow = lane & 15, lq = lane >> 4;

  f32x4 acc[MT][TN];
  const f32x4 z = {0.f, 0.f, 0.f, 0.f};
  #pragma unroll
  for (int i = 0; i < MT; i++)
    #pragma unroll
    for (int j = 0; j < TN; j++) acc[i][j] = z;

  auto stage = [&](int t, int d) {
    const int k0 = t * 32;
    {
      int r = tid >> 2, kc = tid & 3;
      int kcs = kc ^ ((r >> 1) & 3);
      async16(&A[(size_t)(m0 + r) * K + k0 + kcs * 8], &Ash[d * ASZ + tid * 8]);
    }
    #pragma unroll
    for (int i = 0; i < 2; i++) {
      int g = i * 256 + tid;
      int r = g >> 2, kc = g & 3;
      int kcs = kc ^ ((r >> 1) & 3);
      async16(&B[(size_t)(n0 + r) * K + k0 + kcs * 8], &Bsh[d * BSZ + g * 8]);
    }
  };

  const int nt = K >> 5;
  stage(0, 0);
  stage(1, 1);
  for (int t = 0; t < nt; t++) {
    if (t + 2 < nt) stage(t + 2, (t + 2) % 3);
    if (t + 2 < nt)      asm volatile("s_waitcnt vmcnt(6)" ::: "memory");
    else if (t + 1 < nt) asm volatile("s_waitcnt vmcnt(3)" ::: "memory");
    else                 asm volatile("s_waitcnt vmcnt(0)" ::: "memory");
    __builtin_amdgcn_s_barrier();

    const int d = t % 3;
    const int ab = d * ASZ, bb = d * BSZ;
    half8 af[MT], bf[TN];
    #pragma unroll
    for (int ti = 0; ti < MT; ti++) {
      int row = wm + ti * 16 + lrow;
      af[ti] = *(const half8*)&Ash[ab + row * 32 + (lq ^ ((row >> 1) & 3)) * 8];
    }
    #pragma unroll
    for (int tj = 0; tj < TN; tj++) {
      int row = wn + tj * 16 + lrow;
      bf[tj] = *(const half8*)&Bsh[bb + row * 32 + (lq ^ ((row >> 1) & 3)) * 8];
    }
    #pragma unroll
    for (int ti = 0; ti < MT; ti++)
      #pragma unroll
      for (int tj = 0; tj < TN; tj++)
        acc[ti][tj] = __builtin_amdgcn_mfma_f32_16x16x32_f16(af[ti], bf[tj], acc[ti][tj], 0, 0, 0);

    if (t + 1 < nt) {
      asm volatile("s_waitcnt lgkmcnt(0)" ::: "memory");
      __builtin_amdgcn_s_barrier();
    }
  }

  #pragma unroll
  for (int ti = 0; ti < MT; ti++) {
    #pragma unroll
    for (int tj = 0; tj < TN; tj++) {
      int row0 = m0 + wm + ti * 16 + lq * 4;
      int col = n0 + wn + tj * 16 + lrow;
      #pragma unroll
      for (int r = 0; r < 4; r++)
        outf[(size_t)(row0 + r) * ldo + col] = acc[ti][tj][r];
    }
  }
}

// output projection: 512 blocks (64x128 tiles), XCD remap, fp32 out.
__global__ __launch_bounds__(256) void gemm_o(const ushort_t* __restrict__ A,
                                              const ushort_t* __restrict__ B,
                                              float* __restrict__ outf) {
  __shared__ __align__(16) ushort_t lds[18432];   // 36 KB
  int bid = blockIdx.x;
  int w = (bid & 7) * 64 + (bid >> 3);
  int n0 = (w & 3) * 128, m0 = (w >> 2) * 64;
  gemm_o_body(A, B, outf, 512, 512, m0, n0, lds);
}

// ---------------- flash attention: fp16, 32x32 core, counted-vmcnt ----------
// (byte-identical to round 8)
__global__ __launch_bounds__(256, 2) void flash_attn(const ushort_t* __restrict__ qb,
                                                     const ushort_t* __restrict__ kb,
                                                     const ushort_t* __restrict__ vtb,
                                                     ushort_t* __restrict__ ob) {
  __shared__ __align__(16) ushort_t Ksh[2][64 * 64];
  __shared__ __align__(16) ushort_t VTs[2][64 * 64];

  const int tid = threadIdx.x;
  const int wave = tid >> 6, lane = tid & 63;
  const int bh = blockIdx.x & 63, qt = blockIdx.x >> 6;
  const int l31 = lane & 31, hi = lane >> 5;

  const ushort_t* Q = qb + (size_t)bh * 65536;
  const ushort_t* Kp = kb + (size_t)bh * 65536;
  const ushort_t* VT = vtb + (size_t)bh * 65536;

  const int qrow0 = qt * 128 + wave * 32;

  half8 qf[4];
  #pragma unroll
  for (int ds = 0; ds < 4; ds++)
    qf[ds] = *(const half8*)&Q[(size_t)(qrow0 + l31) * 64 + ds * 16 + hi * 8];

  f32x16 oacc[2];
  oacc[0] = zero16();
  oacc[1] = zero16();
  float m_i = -1e30f, l_i = 0.f;

  const int r7 = l31 & 7;
  int pc[4];
  #pragma unroll
  for (int i = 0; i < 4; i++) pc[i] = (((2 * i + hi) ^ r7) << 3);
  const int ro0 = l31 * 64, ro1 = ro0 + 2048;

  auto stage = [&](int kt, int d) {
    #pragma unroll
    for (int i = 0; i < 2; i++) {
      int g = i * 256 + tid, rw = g >> 3, ch = g & 7;
      int co = ((ch ^ (rw & 7)) << 3);
      int lofs = rw * 64 + (ch << 3);
      async16(&Kp[(size_t)(kt * 64 + rw) * 64 + co], &Ksh[d][lofs]);
      async16(&VT[(size_t)rw * 1024 + kt * 64 + co], &VTs[d][lofs]);
    }
  };

  stage(0, 0);

  for (int kt = 0; kt < 16; kt++) {
    const int cur = kt & 1;
    if (kt < 15) {
      stage(kt + 1, cur ^ 1);
      asm volatile("s_waitcnt vmcnt(4)" ::: "memory");
    } else {
      asm volatile("s_waitcnt vmcnt(0)" ::: "memory");
    }
    __builtin_amdgcn_s_barrier();

    f32x16 sacc0 = zero16(), sacc1 = zero16();
    __builtin_amdgcn_s_setprio(1);
    #pragma unroll
    for (int ds = 0; ds < 4; ds++) {
      half8 k0 = *(const half8*)&Ksh[cur][ro0 + pc[ds]];
      half8 k1 = *(const half8*)&Ksh[cur][ro1 + pc[ds]];
      sacc0 = __builtin_amdgcn_mfma_f32_32x32x16_f16(k0, qf[ds], sacc0, 0, 0, 0);
      sacc1 = __builtin_amdgcn_mfma_f32_32x32x16_f16(k1, qf[ds], sacc1, 0, 0, 0);
    }
    __builtin_amdgcn_s_setprio(0);

    float mx = -1e30f;
    #pragma unroll
    for (int r = 0; r < 16; r++) {
      mx = fmaxf(mx, sacc0[r]);
      mx = fmaxf(mx, sacc1[r]);
    }
    mx = fmaxf(mx, __shfl_xor(mx, 32));
    float mnew = fmaxf(m_i, mx);
    float mL = mnew * LOG2E;
    float alpha = exp2f(fmaf(m_i, LOG2E, -mL));
    float sum = 0.f;
    unsigned pw[16];
    #pragma unroll
    for (int j = 0; j < 8; j++) {
      float p0 = exp2f(fmaf(sacc0[2 * j], LOG2E, -mL));
      float p1 = exp2f(fmaf(sacc0[2 * j + 1], LOG2E, -mL));
      sum += p0 + p1;
      asm("v_cvt_pkrtz_f16_f32 %0, %1, %2" : "=v"(pw[j]) : "v"(p0), "v"(p1));
    }
    #pragma unroll
    for (int j = 0; j < 8; j++) {
      float p0 = exp2f(fmaf(sacc1[2 * j], LOG2E, -mL));
      float p1 = exp2f(fmaf(sacc1[2 * j + 1], LOG2E, -mL));
      sum += p0 + p1;
      asm("v_cvt_pkrtz_f16_f32 %0, %1, %2" : "=v"(pw[8 + j]) : "v"(p0), "v"(p1));
    }
    sum += __shfl_xor(sum, 32);
    l_i = fmaf(l_i, alpha, sum);
    m_i = mnew;
    #pragma unroll
    for (int r = 0; r < 16; r++) {
      oacc[0][r] *= alpha;
      oacc[1][r] *= alpha;
    }

    __builtin_amdgcn_s_setprio(1);
    #pragma unroll
    for (int ks = 0; ks < 4; ks++) {
      const int base = (ks >> 1) * 8 + (ks & 1) * 4;
      uint2v s0 = __builtin_amdgcn_permlane32_swap(pw[base + 0], pw[base + 2], false, false);
      uint2v s1 = __builtin_amdgcn_permlane32_swap(pw[base + 1], pw[base + 3], false, false);
      half8 pfrag = u4h8((uint4v){s0.x, s1.x, s0.y, s1.y});
      half8 vf0 = *(const half8*)&VTs[cur][ro0 + pc[ks]];
      half8 vf1 = *(const half8*)&VTs[cur][ro1 + pc[ks]];
      oacc[0] = __builtin_amdgcn_mfma_f32_32x32x16_f16(vf0, pfrag, oacc[0], 0, 0, 0);
      oacc[1] = __builtin_amdgcn_mfma_f32_32x32x16_f16(vf1, pfrag, oacc[1], 0, 0, 0);
    }
    __builtin_amdgcn_s_setprio(0);

    if (kt < 15) {
      asm volatile("s_waitcnt lgkmcnt(0)" ::: "memory");
      __builtin_amdgcn_s_barrier();
    }
  }

  const int b = bh >> 3, h = bh & 7;
  const int n = qrow0 + l31;
  float rinv = 1.f / l_i;
  #pragma unroll
  for (int dt = 0; dt < 2; dt++) {
    #pragma unroll
    for (int t = 0; t < 4; t++) {
      ushort_t hv[4];
      #pragma unroll
      for (int e = 0; e < 4; e++)
        hv[e] = f2h(oacc[dt][4 * t + e] * rinv);
      size_t idx = (size_t)(b * 1024 + n) * 512 + h * 64 + dt * 32 + t * 8 + hi * 4;
      *(uint2v*)&ob[idx] = (uint2v){(unsigned)hv[0] | ((unsigned)hv[1] << 16),
                                    (unsigned)hv[2] | ((unsigned)hv[3] << 16)};
    }
  }
}

// ---------------- launcher ----------------
extern "C" void kernel_launch(void* const* d_in, const int* in_sizes, int n_in,
                              void* d_out, int out_size, void* d_ws, size_t ws_size,
                              hipStream_t stream) {
  const float* cur = (const float*)d_in[0];   // [8,1024,512] fp32
  const float* hid = (const float*)d_in[1];   // [8,1024,512] fp32
  const float* Wq  = (const float*)d_in[2];   // [512,512]
  const float* Wkv = (const float*)d_in[3];   // [512,1024]
  const float* Wo  = (const float*)d_in[4];   // [512,512]

  ushort_t* ws = (ushort_t*)d_ws;
  ushort_t* ko  = ws;                   // 4,194,304  (k, k-layout)
  ushort_t* vt  = ko + 4194304;         // 4,194,304  (v^T layout)
  ushort_t* qo  = vt + 4194304;         // 4,194,304  (q, q-layout)
  ushort_t* ao  = qo + 4194304;         // 4,194,304  (attn out, fp16)
  ushort_t* WqT = ao + 4194304;         // 262,144
  ushort_t* WkvT = WqT + 262144;        // 524,288
  ushort_t* WoT = WkvT + 524288;        // 262,144

  // weight transpose+cast only (activation cast fused into gemm_qkv)
  prep_w<<<1024, 256, 0, stream>>>(Wq, Wkv, Wo, WqT, WkvT, WoT);

  // merged kv + q projections with fused fp32->fp16 A-cast
  gemm_qkv<<<768, 256, 0, stream>>>(hid, WkvT, ko, vt, cur, WqT, qo);

  // attention: 512 blocks (head-major XCD grouping), 128 q-rows/block
  flash_attn<<<512, 256, 0, stream>>>(qo, ko, vt, ao);

  // output projection: 512 blocks -> fp32 d_out
  gemm_o<<<512, 256, 0, stream>>>(ao, WoT, (float*)d_out);
}